// Round 3
// baseline (143.053 us; speedup 1.0000x reference)
//
#include <hip/hip_runtime.h>
#include <stdint.h>

typedef __attribute__((ext_vector_type(4))) float f32x4;
typedef __attribute__((ext_vector_type(8))) short bf16x8;

#define C_NORM_LOG2E 0.18033688011112043f

__device__ __forceinline__ uint32_t swz(uint32_t a) { return a ^ (((a >> 7) & 7u) << 4); }

__device__ __forceinline__ uint32_t cvt_pk_bf16(float a, float b) {
  uint32_t r;
  asm("v_cvt_pk_bf16_f32 %0, %1, %2" : "=v"(r) : "v"(a), "v"(b));
  return r;
}

__device__ __forceinline__ float2 unpk_bf16(uint32_t u) {
  float2 f;
  f.x = __uint_as_float(u << 16);
  f.y = __uint_as_float(u & 0xffff0000u);
  return f;
}

__device__ __forceinline__ ushort f2bf(float f) {
  uint32_t u = __float_as_uint(f);
  u += 0x7FFFu + ((u >> 16) & 1u);
  return (ushort)(u >> 16);
}

// ---- pack (merged): Wp [192][512] bf16 (Wq|Wk|Wv) and PEdT[m][n] = PE[2n][2m]*NORM*log2e ----
__global__ void pack_kernel(const float* __restrict__ Wk, const float* __restrict__ Wq,
                            const float* __restrict__ Wv, const float* __restrict__ PE,
                            ushort* __restrict__ Wp, float* __restrict__ PEdT) {
  int bid = blockIdx.x;
  if (bid < 384) {
    int i = bid * 256 + threadIdx.x;  // 192*512
    int n = i >> 9, e = i & 511;
    float val = (n < 64) ? Wq[n * 512 + e]
              : (n < 128) ? Wk[(n - 64) * 512 + e]
                          : Wv[(n - 128) * 512 + e];
    Wp[i] = f2bf(val);
  } else {
    int i = (bid - 384) * 256 + threadIdx.x;  // 512*512
    int m = i >> 9, n = i & 511;
    PEdT[i] = PE[n * 2048 + m * 2] * C_NORM_LOG2E;
  }
}

// ---------------- projection: QKV[r][d] bf16, r = (b*16+s)*512 + m, from x[b, 32m+s, :] ----------
__global__ __launch_bounds__(512, 4) void proj_kernel(
    const float* __restrict__ x, const ushort* __restrict__ Wp,
    ushort* __restrict__ Qw, ushort* __restrict__ Kw, ushort* __restrict__ Vw) {
  __shared__ char Xl[16384];  // 128 rows x 64 bf16, swizzled
  const int tid = threadIdx.x;
  const int w = tid >> 6, lane = tid & 63, g = lane >> 4, l15 = lane & 15;
  const int wr = w >> 2, wc = w & 3;  // 2x4 wave grid: 64 rows x 48 cols each
  const int R0 = blockIdx.x * 128;    // grid 512
  const int b = R0 >> 13, s = (R0 >> 9) & 15, m0 = R0 & 511;
  const int rl = tid >> 2, c4 = tid & 3;
  const float* rowp = x + (size_t)b * 8388608 + (size_t)s * 512 +
                      (size_t)(m0 + rl) * 16384 + c4 * 4;
  const uint32_t lb = rl * 128 + c4 * 8;

  f32x4 acc[4][3];
#pragma unroll
  for (int i = 0; i < 4; ++i)
#pragma unroll
    for (int j = 0; j < 3; ++j) acc[i][j] = (f32x4){0.f, 0.f, 0.f, 0.f};

  float4 R[2][4];
#pragma unroll
  for (int j = 0; j < 4; ++j) R[0][j] = *(const float4*)(rowp + j * 16);

#pragma unroll
  for (int kt = 0; kt < 8; ++kt) {
    const int cur = kt & 1;
    if (kt) __syncthreads();  // Xl free (prev compute done)
#pragma unroll
    for (int j = 0; j < 4; ++j) {
      uint2 u;
      u.x = cvt_pk_bf16(R[cur][j].x, R[cur][j].y);
      u.y = cvt_pk_bf16(R[cur][j].z, R[cur][j].w);
      *(uint2*)(Xl + swz(lb + j * 32)) = u;
    }
    if (kt < 7) {
#pragma unroll
      for (int j = 0; j < 4; ++j)
        R[cur ^ 1][j] = *(const float4*)(rowp + (kt + 1) * 64 + j * 16);
    }
    __syncthreads();  // Xl ready; next-tile loads in flight during compute
#pragma unroll
    for (int kd = 0; kd < 2; ++kd) {
      bf16x8 bb[3];
#pragma unroll
      for (int j = 0; j < 3; ++j)
        bb[j] = *(const bf16x8*)((const char*)Wp + (size_t)(wc * 48 + j * 16 + l15) * 1024 +
                                 kt * 128 + kd * 64 + g * 16);
      bf16x8 a[4];
#pragma unroll
      for (int i = 0; i < 4; ++i)
        a[i] = *(const bf16x8*)(Xl + swz((wr * 64 + i * 16 + l15) * 128 + kd * 64 + g * 16));
#pragma unroll
      for (int i = 0; i < 4; ++i)
#pragma unroll
        for (int j = 0; j < 3; ++j)
          acc[i][j] = __builtin_amdgcn_mfma_f32_16x16x32_bf16(a[i], bb[j], acc[i][j], 0, 0, 0);
    }
  }
  // epilogue: D layout col = l15 (n), row = g*4 + r
#pragma unroll
  for (int i = 0; i < 4; ++i) {
    int rl2 = wr * 64 + i * 16 + g * 4;
    size_t rbase = (size_t)(R0 + rl2) * 64;
#pragma unroll
    for (int j = 0; j < 3; ++j) {
      int n = wc * 48 + j * 16 + l15;
      int sel = n >> 6, d = n & 63;
      ushort* dst = (sel == 0) ? Qw : (sel == 1) ? Kw : Vw;
      dst += rbase + d;
#pragma unroll
      for (int r = 0; r < 4; ++r) dst[(size_t)r * 64] = f2bf(acc[i][j][r]);
    }
  }
}

// ------- attention, chunked over n: block = (bs, c), rows n in [128c,128c+128) -------
// Balanced waves: wave w covers m in [w*16*(c+1), (w+1)*16*(c+1)). No-max softmax over m.
__global__ __launch_bounds__(512, 4) void attn_kernel(
    const ushort* __restrict__ Qw, const ushort* __restrict__ Kw,
    const ushort* __restrict__ Vw, const float* __restrict__ PEdT,
    ushort* __restrict__ Pp) {
  __shared__ char Vtl[8192];    // V^T tile [64 d][64 n] bf16, swizzled
  __shared__ char Ptl[65536];   // per-wave P^T [<=64 m][64 n] bf16, swizzled
  __shared__ float red[512];    // [wave][row]
  __shared__ float rZrow[64];

  const int tid = threadIdx.x;
  const int w = tid >> 6, lane = tid & 63, g = lane >> 4, l15 = lane & 15;
  const int bid = blockIdx.x;
  const int bs = bid >> 2, c = bid & 3;  // 128 bs x 4 chunks
  const int nmf = c + 1;                 // 16-row m-fragments per wave
  const int wb = w * 16 * nmf;           // wave m-base
  const size_t base = (size_t)bs * 32768;
  const char* Qb = (const char*)(Qw + base);
  const char* Kb = (const char*)(Kw + base);
  const char* Vb = (const char*)(Vw + base);

  const int vrow = tid >> 3, vseg = tid & 7;
  uint4 dv = *(const uint4*)(Vb + 2 * c * 8192 + vrow * 128 + vseg * 16);

  f32x4 att[4][4];
#pragma unroll
  for (int i = 0; i < 4; ++i)
#pragma unroll
    for (int j = 0; j < 4; ++j) att[i][j] = (f32x4){0.f, 0.f, 0.f, 0.f};

#pragma unroll
  for (int it = 0; it < 2; ++it) {
    const int nt = 2 * c + it;
    // scatter V^T into LDS
    {
      uint32_t dwv[4] = {dv.x, dv.y, dv.z, dv.w};
#pragma unroll
      for (int t = 0; t < 4; ++t) {
        int d0 = vseg * 8 + t * 2;
        *(ushort*)(Vtl + swz((uint32_t)(d0 * 128 + vrow * 2))) = (ushort)(dwv[t] & 0xffffu);
        *(ushort*)(Vtl + swz((uint32_t)((d0 + 1) * 128 + vrow * 2))) = (ushort)(dwv[t] >> 16);
      }
    }
    if (it == 0) dv = *(const uint4*)(Vb + (2 * c + 1) * 8192 + vrow * 128 + vseg * 16);
    __syncthreads();  // B1: Vtl ready

    // Q fragments for this wave's m-slice (live only through QK^T)
    bf16x8 bQ[4][2];
#pragma unroll
    for (int mf = 0; mf < 4; ++mf)
      if (mf < nmf) {
#pragma unroll
        for (int kd = 0; kd < 2; ++kd)
          bQ[mf][kd] = *(const bf16x8*)(Qb + (size_t)(wb + mf * 16 + l15) * 128 + kd * 64 + g * 16);
      }

    uint32_t Ppk[4][4][2];  // unnormalized exp'd P, packed bf16 pairs (r01, r23)
    float ls[4][4];
#pragma unroll
    for (int nf = 0; nf < 4; ++nf) {
      bf16x8 aK[2];
#pragma unroll
      for (int kd = 0; kd < 2; ++kd)
        aK[kd] = *(const bf16x8*)(Kb + nt * 8192 + (size_t)(nf * 16 + l15) * 128 + kd * 64 + g * 16);
      f32x4 S[4];
#pragma unroll
      for (int mf = 0; mf < 4; ++mf)
        if (mf < nmf) {
          f32x4 cc = (f32x4){0.f, 0.f, 0.f, 0.f};
          cc = __builtin_amdgcn_mfma_f32_16x16x32_bf16(aK[0], bQ[mf][0], cc, 0, 0, 0);
          cc = __builtin_amdgcn_mfma_f32_16x16x32_bf16(aK[1], bQ[mf][1], cc, 0, 0, 0);
          S[mf] = cc;
        }
      const int nb = nt * 64 + nf * 16 + g * 4;
      float l0 = 0.f, l1 = 0.f, l2 = 0.f, l3 = 0.f;
#pragma unroll
      for (int mf = 0; mf < 4; ++mf)
        if (mf < nmf) {
          int m_ = wb + mf * 16 + l15;
          f32x4 pe = *(const f32x4*)(PEdT + (size_t)m_ * 512 + nb);
          float e0 = (nb + 0 >= m_) ? exp2f(fmaf(S[mf][0], C_NORM_LOG2E, pe[0])) : 0.f;
          float e1 = (nb + 1 >= m_) ? exp2f(fmaf(S[mf][1], C_NORM_LOG2E, pe[1])) : 0.f;
          float e2 = (nb + 2 >= m_) ? exp2f(fmaf(S[mf][2], C_NORM_LOG2E, pe[2])) : 0.f;
          float e3 = (nb + 3 >= m_) ? exp2f(fmaf(S[mf][3], C_NORM_LOG2E, pe[3])) : 0.f;
          l0 += e0; l1 += e1; l2 += e2; l3 += e3;
          Ppk[nf][mf][0] = cvt_pk_bf16(e0, e1);
          Ppk[nf][mf][1] = cvt_pk_bf16(e2, e3);
        }
      ls[nf][0] = l0; ls[nf][1] = l1; ls[nf][2] = l2; ls[nf][3] = l3;
    }

    // sum over m: butterfly across 16 lanes, then across 8 waves via LDS
#pragma unroll
    for (int msk = 1; msk < 16; msk <<= 1)
#pragma unroll
      for (int nf = 0; nf < 4; ++nf)
#pragma unroll
        for (int r = 0; r < 4; ++r) ls[nf][r] += __shfl_xor(ls[nf][r], msk, 16);
    if (l15 == 0) {
#pragma unroll
      for (int nf = 0; nf < 4; ++nf)
#pragma unroll
        for (int r = 0; r < 4; ++r) red[w * 64 + nf * 16 + g * 4 + r] = ls[nf][r];
    }
    __syncthreads();  // B2
    if (tid < 64) {
      float z = red[tid];
#pragma unroll
      for (int j = 1; j < 8; ++j) z += red[j * 64 + tid];
      rZrow[tid] = 1.0f / z;
    }
    __syncthreads();  // B3

    // normalize (unpack, scale, repack), write own-wave P^T to LDS
    char* Pw = Ptl + w * 8192;
#pragma unroll
    for (int nf = 0; nf < 4; ++nf) {
      float z0 = rZrow[nf * 16 + g * 4 + 0];
      float z1 = rZrow[nf * 16 + g * 4 + 1];
      float z2 = rZrow[nf * 16 + g * 4 + 2];
      float z3 = rZrow[nf * 16 + g * 4 + 3];
#pragma unroll
      for (int mf = 0; mf < 4; ++mf)
        if (mf < nmf) {
          float2 ab = unpk_bf16(Ppk[nf][mf][0]);
          float2 cd = unpk_bf16(Ppk[nf][mf][1]);
          uint2 u;
          u.x = cvt_pk_bf16(ab.x * z0, ab.y * z1);
          u.y = cvt_pk_bf16(cd.x * z2, cd.y * z3);
          *(uint2*)(Pw + swz((uint32_t)((mf * 16 + l15) * 128 + nf * 32 + g * 8))) = u;
        }
    }
    // P^T V
#pragma unroll
    for (int kf = 0; kf < 2; ++kf) {
      bf16x8 bV[4];
#pragma unroll
      for (int df = 0; df < 4; ++df)
        bV[df] = *(const bf16x8*)(Vtl + swz((uint32_t)((df * 16 + l15) * 128 + kf * 64 + g * 16)));
#pragma unroll
      for (int mf = 0; mf < 4; ++mf)
        if (mf < nmf) {
          bf16x8 aP = *(const bf16x8*)(Pw + swz((uint32_t)((mf * 16 + l15) * 128 + kf * 64 + g * 16)));
#pragma unroll
          for (int df = 0; df < 4; ++df)
            att[mf][df] = __builtin_amdgcn_mfma_f32_16x16x32_bf16(aP, bV[df], att[mf][df], 0, 0, 0);
        }
    }
    __syncthreads();  // B4: protect Vtl/red for next tile
  }

  // epilogue: bf16 partial att^c at Pp[(c*128+bs)*32768 + m*64 + d]; only rows m < 128*(c+1)
  ushort* pb = Pp + ((size_t)c * 128 + bs) * 32768;
#pragma unroll
  for (int mf = 0; mf < 4; ++mf)
    if (mf < nmf) {
#pragma unroll
      for (int df = 0; df < 4; ++df)
#pragma unroll
        for (int r = 0; r < 4; ++r) {
          int m_ = wb + mf * 16 + g * 4 + r;
          pb[(size_t)m_ * 64 + df * 16 + l15] = f2bf(att[mf][df][r]);
        }
    }
}

// ---------------- reduce: out[b,2m',d] = sum over valid chunks, out[b,odd,d] = 0 ----------------
__global__ void reduce_kernel(const ushort* __restrict__ Pp, float* __restrict__ out) {
  int jj = blockIdx.x * 256 + threadIdx.x;  // 524288 threads, grid 2048
  int d8 = jj & 7, m = (jj >> 3) & 511, bs = jj >> 12;
  const size_t ji = ((size_t)bs * 512 + m) * 64 + d8 * 8;
  float f[8];
#pragma unroll
  for (int e = 0; e < 8; ++e) f[e] = 0.f;
  for (int cc = m >> 7; cc < 4; ++cc) {  // chunk cc covers m < 128*(cc+1)
    uint4 v = *(const uint4*)(Pp + (size_t)cc * 4194304 + ji);
    uint32_t dw[4] = {v.x, v.y, v.z, v.w};
#pragma unroll
    for (int t = 0; t < 4; ++t) {
      f[t * 2] += __uint_as_float(dw[t] << 16);
      f[t * 2 + 1] += __uint_as_float(dw[t] & 0xffff0000u);
    }
  }
  int b = bs >> 4, s = bs & 15;
  size_t t0 = 2 * ((size_t)s * 512 + m);
  float* ob = out + (size_t)b * 1048576 + t0 * 64 + d8 * 8;
  *(float4*)(ob) = (float4){f[0], f[1], f[2], f[3]};
  *(float4*)(ob + 4) = (float4){f[4], f[5], f[6], f[7]};
  *(float4*)(ob + 64) = (float4){0.f, 0.f, 0.f, 0.f};
  *(float4*)(ob + 68) = (float4){0.f, 0.f, 0.f, 0.f};
}

extern "C" void kernel_launch(void* const* d_in, const int* in_sizes, int n_in,
                              void* d_out, int out_size, void* d_ws, size_t ws_size,
                              hipStream_t stream) {
  const float* x  = (const float*)d_in[0];
  const float* Wk = (const float*)d_in[1];
  const float* Wq = (const float*)d_in[2];
  const float* Wv = (const float*)d_in[3];
  const float* PE = (const float*)d_in[4];
  float* out = (float*)d_out;
  char* ws = (char*)d_ws;

  ushort* Qw   = (ushort*)(ws);              // 8 MB
  ushort* Kw   = (ushort*)(ws + 8388608);    // 8 MB
  ushort* Vw   = (ushort*)(ws + 16777216);   // 8 MB
  ushort* Wp   = (ushort*)(ws + 25165824);   // 192 KB
  float*  PEdT = (float*)(ws + 25362432);    // 1 MB
  ushort* Pp   = (ushort*)(ws + 33554432);   // 32 MB partials (4 chunks)

  pack_kernel<<<dim3(1408), dim3(256), 0, stream>>>(Wk, Wq, Wv, PE, Wp, PEdT);
  proj_kernel<<<dim3(512), dim3(512), 0, stream>>>(x, Wp, Qw, Kw, Vw);
  attn_kernel<<<dim3(512), dim3(512), 0, stream>>>(Qw, Kw, Vw, PEdT, Pp);
  reduce_kernel<<<dim3(2048), dim3(256), 0, stream>>>(Pp, out);
}

// Round 5
// 113.837 us; speedup vs baseline: 1.2567x; 1.2567x over previous
//
#include <hip/hip_runtime.h>
#include <stdint.h>

typedef __attribute__((ext_vector_type(4))) float f32x4;
typedef __attribute__((ext_vector_type(8))) short bf16x8;
typedef __attribute__((ext_vector_type(4))) unsigned int u32x4;

#define C_NORM_LOG2E 0.18033688011112043f

// 128B-row swizzle (rows of 64 bf16 / 32 f32... generic: XOR row&7 into byte bits 4-6)
__device__ __forceinline__ uint32_t swz(uint32_t a) { return a ^ (((a >> 7) & 7u) << 4); }
// 64B-row swizzle for the P half-tile (XOR (row>>1)&3 into bits 4-5; row-preserving)
__device__ __forceinline__ uint32_t swzP(uint32_t a) { return a ^ (((a >> 7) & 3u) << 4); }

__device__ __forceinline__ uint32_t cvt_pk_bf16(float a, float b) {
  uint32_t r;
  asm("v_cvt_pk_bf16_f32 %0, %1, %2" : "=v"(r) : "v"(a), "v"(b));
  return r;
}

__device__ __forceinline__ float2 unpk_bf16(uint32_t u) {
  float2 f;
  f.x = __uint_as_float(u << 16);
  f.y = __uint_as_float(u & 0xffff0000u);
  return f;
}

__device__ __forceinline__ ushort f2bf(float f) {
  uint32_t u = __float_as_uint(f);
  u += 0x7FFFu + ((u >> 16) & 1u);
  return (ushort)(u >> 16);
}

__device__ __forceinline__ void gl_lds16(const void* gp, void* lp) {
  __builtin_amdgcn_global_load_lds((const __attribute__((address_space(1))) void*)gp,
                                   (__attribute__((address_space(3))) void*)lp, 16, 0, 0);
}

// ---- pack: Wp [192][512] bf16 (Wq|Wk|Wv) and PEdT[m][n] = PE[2n][2m]*NORM*log2e ----
__global__ void pack_kernel(const float* __restrict__ Wk, const float* __restrict__ Wq,
                            const float* __restrict__ Wv, const float* __restrict__ PE,
                            ushort* __restrict__ Wp, float* __restrict__ PEdT) {
  int bid = blockIdx.x;
  if (bid < 384) {
    int i = bid * 256 + threadIdx.x;  // 192*512
    int n = i >> 9, e = i & 511;
    float val = (n < 64) ? Wq[n * 512 + e]
              : (n < 128) ? Wk[(n - 64) * 512 + e]
                          : Wv[(n - 128) * 512 + e];
    Wp[i] = f2bf(val);
  } else {
    int i = (bid - 384) * 256 + threadIdx.x;  // 512*512
    int m = i >> 9, n = i & 511;
    PEdT[i] = PE[n * 2048 + m * 2] * C_NORM_LOG2E;
  }
}

// ---------------- projection: QKV[r][d] bf16, r = (b*16+s)*512 + m, from x[b, 32m+s, :] --------
// f32 LDS double-buffer via global_load_lds (pre-swizzled source), frag read = 2x ds_read_b128+cvt
__global__ __launch_bounds__(512, 4) void proj_kernel(
    const float* __restrict__ x, const ushort* __restrict__ Wp,
    ushort* __restrict__ Qw, ushort* __restrict__ Kw, ushort* __restrict__ Vw) {
  __shared__ float Xl[2][8192];  // 2 x 32KB: 128 rows x 64 f32, swizzled
  const int tid = threadIdx.x;
  const int lane = tid & 63, w = tid >> 6, g = lane >> 4, l15 = lane & 15;
  const int wr = w >> 2, wc = w & 3;  // 2x4 wave grid: 64 rows x 48 cols each
  // XCD swizzle: all 4 parts of segment bs land on XCD bs%8
  const int bid = blockIdx.x;
  const int xcd = bid & 7, idx = bid >> 3;
  const int part = idx & 3, h = idx >> 2;
  const int bs = h * 8 + xcd;
  const int m0 = part * 128;
  const int R0 = bs * 512 + m0;
  const int b = bs >> 4, s = bs & 15;
  const char* xb = (const char*)x + ((size_t)b * 8388608 + (size_t)s * 512) * 4;

  f32x4 acc[4][3];
#pragma unroll
  for (int i = 0; i < 4; ++i)
#pragma unroll
    for (int j = 0; j < 3; ++j) acc[i][j] = (f32x4){0.f, 0.f, 0.f, 0.f};

  auto stage = [&](int kt, int buf) {
#pragma unroll
    for (int j = 0; j < 4; ++j) {
      uint32_t sl = (uint32_t)(j * 8192 + tid * 16);      // linear LDS byte slot
      uint32_t t = sl ^ (((sl >> 8) & 7u) << 4);          // pre-swizzled source index
      uint32_t row = t >> 8, colb = t & 255u;
      const char* src = xb + (size_t)(m0 + row) * 65536 + (size_t)kt * 256 + colb;
      gl_lds16(src, (char*)&Xl[buf][0] + sl);
    }
  };

  stage(0, 0);
  __syncthreads();
#pragma unroll
  for (int kt = 0; kt < 8; ++kt) {
    const int buf = kt & 1;
    if (kt < 7) stage(kt + 1, buf ^ 1);
#pragma unroll
    for (int kd = 0; kd < 2; ++kd) {
      bf16x8 bb[3];
#pragma unroll
      for (int j = 0; j < 3; ++j)
        bb[j] = *(const bf16x8*)((const char*)Wp + (size_t)(wc * 48 + j * 16 + l15) * 1024 +
                                 kt * 128 + kd * 64 + g * 16);
      bf16x8 a[4];
#pragma unroll
      for (int i = 0; i < 4; ++i) {
        int Rr = wr * 64 + i * 16 + l15;
        uint32_t a32 = (uint32_t)(Rr * 256 + kd * 128 + g * 32);
        // swizzled space is not +16-translation-invariant: both granules via XOR
        uint32_t off0 = a32 ^ ((uint32_t)(Rr & 7) << 4);
        uint32_t off1 = off0 ^ 16u;
        f32x4 lo = *(const f32x4*)((const char*)&Xl[buf][0] + off0);
        f32x4 hi = *(const f32x4*)((const char*)&Xl[buf][0] + off1);
        uint32_t uu[4];
        uu[0] = cvt_pk_bf16(lo[0], lo[1]);
        uu[1] = cvt_pk_bf16(lo[2], lo[3]);
        uu[2] = cvt_pk_bf16(hi[0], hi[1]);
        uu[3] = cvt_pk_bf16(hi[2], hi[3]);
        a[i] = *(bf16x8*)uu;
      }
#pragma unroll
      for (int i = 0; i < 4; ++i)
#pragma unroll
        for (int j = 0; j < 3; ++j)
          acc[i][j] = __builtin_amdgcn_mfma_f32_16x16x32_bf16(a[i], bb[j], acc[i][j], 0, 0, 0);
    }
    __syncthreads();
  }
  // epilogue: D layout col = l15 (n), row = g*4 + r
#pragma unroll
  for (int i = 0; i < 4; ++i) {
    int rl2 = wr * 64 + i * 16 + g * 4;
    size_t rbase = (size_t)(R0 + rl2) * 64;
#pragma unroll
    for (int j = 0; j < 3; ++j) {
      int n = wc * 48 + j * 16 + l15;
      int sel = n >> 6, d = n & 63;
      ushort* dst = (sel == 0) ? Qw : (sel == 1) ? Kw : Vw;
      dst += rbase + d;
#pragma unroll
      for (int r = 0; r < 4; ++r) dst[(size_t)r * 64] = f2bf(acc[i][j][r]);
    }
  }
}

// ------- attention, chunked over n: block = (bs, c), rows n in [128c,128c+128) -------
// Balanced waves (wave w: m in [w*16*(c+1), ...)). No-max softmax. 1/Z folded into V frags.
__global__ __launch_bounds__(512, 4) void attn_kernel(
    const ushort* __restrict__ Qw, const ushort* __restrict__ Kw,
    const ushort* __restrict__ Vw, const float* __restrict__ PEdT,
    ushort* __restrict__ Pp) {
  __shared__ char Vtl[16384];   // 2 x [64 d][64 n] bf16 V^T tiles, swizzled
  __shared__ char Ptl[32768];   // per-wave 4KB: [64 m][32 n] bf16 half-tile, swizzled
  __shared__ float red[512];    // [wave][row]
  __shared__ float rZrow[64];

  const int tid = threadIdx.x;
  const int w = tid >> 6, lane = tid & 63, g = lane >> 4, l15 = lane & 15;
  // XCD swizzle: 4 chunks of bs on XCD bs%8; gray-code chunk order pairs (0,3),(1,2) per CU
  const int bid = blockIdx.x;
  const int xcd = bid & 7, idx = bid >> 3;
  const int bs = (idx & 15) * 8 + xcd;
  const int co = idx >> 4;
  const int c = co ^ (co >> 1);
  const int nmf = c + 1;           // 16-row m-fragments per wave
  const int wb = w * 16 * nmf;     // wave m-base
  const size_t base = (size_t)bs * 32768;
  const char* Qb = (const char*)(Qw + base);
  const char* Kb = (const char*)(Kw + base);
  const char* Vb = (const char*)(Vw + base);
  char* Pw = Ptl + w * 4096;

  const int vrow = tid >> 3, vseg = tid & 7;
  auto scatter = [&](uint4 d4, int buf) {
    uint32_t dwv[4] = {d4.x, d4.y, d4.z, d4.w};
#pragma unroll
    for (int t = 0; t < 4; ++t) {
      int d0 = vseg * 8 + t * 2;
      *(ushort*)(Vtl + buf * 8192 + swz((uint32_t)(d0 * 128 + vrow * 2))) = (ushort)(dwv[t] & 0xffffu);
      *(ushort*)(Vtl + buf * 8192 + swz((uint32_t)((d0 + 1) * 128 + vrow * 2))) = (ushort)(dwv[t] >> 16);
    }
  };

  uint4 dv = *(const uint4*)(Vb + (size_t)(2 * c) * 8192 + vrow * 128 + vseg * 16);
  scatter(dv, 0);
  dv = *(const uint4*)(Vb + (size_t)(2 * c + 1) * 8192 + vrow * 128 + vseg * 16);
  __syncthreads();  // B0: Vtl[0] ready

  f32x4 att[4][4];
#pragma unroll
  for (int i = 0; i < 4; ++i)
#pragma unroll
    for (int j = 0; j < 4; ++j) att[i][j] = (f32x4){0.f, 0.f, 0.f, 0.f};

#pragma unroll
  for (int it = 0; it < 2; ++it) {
    const int nt = 2 * c + it;
    if (it == 0) scatter(dv, 1);  // Vtl[1]; ordered vs all reads by B2/B3 chain

    uint32_t Ppk2[2][4][2];  // nf=2,3 packed P held in regs
    float ls[4][4];
    // --- a: QK^T + bias/mask + exp2 + pack; nf<2 -> LDS half-tile, nf>=2 -> regs
#pragma unroll
    for (int nf = 0; nf < 4; ++nf) {
      bf16x8 aK[2];
#pragma unroll
      for (int kd = 0; kd < 2; ++kd)
        aK[kd] = *(const bf16x8*)(Kb + (size_t)nt * 8192 + (size_t)(nf * 16 + l15) * 128 +
                                  kd * 64 + g * 16);
      const int nb = nt * 64 + nf * 16 + g * 4;
      float l0 = 0.f, l1 = 0.f, l2 = 0.f, l3 = 0.f;
#pragma unroll
      for (int mf = 0; mf < 4; ++mf)
        if (mf < nmf) {
          const char* qrow = Qb + (size_t)(wb + mf * 16 + l15) * 128;
          bf16x8 q0 = *(const bf16x8*)(qrow + g * 16);
          bf16x8 q1 = *(const bf16x8*)(qrow + 64 + g * 16);
          f32x4 S = (f32x4){0.f, 0.f, 0.f, 0.f};
          S = __builtin_amdgcn_mfma_f32_16x16x32_bf16(aK[0], q0, S, 0, 0, 0);
          S = __builtin_amdgcn_mfma_f32_16x16x32_bf16(aK[1], q1, S, 0, 0, 0);
          int m_ = wb + mf * 16 + l15;
          f32x4 pe = *(const f32x4*)(PEdT + (size_t)m_ * 512 + nb);
          float e0 = (nb + 0 >= m_) ? exp2f(fmaf(S[0], C_NORM_LOG2E, pe[0])) : 0.f;
          float e1 = (nb + 1 >= m_) ? exp2f(fmaf(S[1], C_NORM_LOG2E, pe[1])) : 0.f;
          float e2 = (nb + 2 >= m_) ? exp2f(fmaf(S[2], C_NORM_LOG2E, pe[2])) : 0.f;
          float e3 = (nb + 3 >= m_) ? exp2f(fmaf(S[3], C_NORM_LOG2E, pe[3])) : 0.f;
          l0 += e0; l1 += e1; l2 += e2; l3 += e3;
          uint32_t ux = cvt_pk_bf16(e0, e1);
          uint32_t uy = cvt_pk_bf16(e2, e3);
          if (nf < 2) {
            uint2 u; u.x = ux; u.y = uy;
            *(uint2*)(Pw + swzP((uint32_t)((mf * 16 + l15) * 64 + (nf & 1) * 32 + g * 8))) = u;
          } else {
            Ppk2[nf - 2][mf][0] = ux;
            Ppk2[nf - 2][mf][1] = uy;
          }
        }
      ls[nf][0] = l0; ls[nf][1] = l1; ls[nf][2] = l2; ls[nf][3] = l3;
    }
    // --- b: butterfly over 16 lanes, stash per-wave partial Z
#pragma unroll
    for (int msk = 1; msk < 16; msk <<= 1)
#pragma unroll
      for (int nf = 0; nf < 4; ++nf)
#pragma unroll
        for (int r = 0; r < 4; ++r) ls[nf][r] += __shfl_xor(ls[nf][r], msk, 16);
    if (l15 == 0) {
#pragma unroll
      for (int nf = 0; nf < 4; ++nf)
#pragma unroll
        for (int r = 0; r < 4; ++r) red[w * 64 + nf * 16 + g * 4 + r] = ls[nf][r];
    }
    __syncthreads();  // B2
    // --- c: parallel rZ (wave w reduces rows 8w..8w+7)
    {
      int row8 = lane >> 3, srcw = lane & 7;
      float v = red[srcw * 64 + w * 8 + row8];
      v += __shfl_xor(v, 1);
      v += __shfl_xor(v, 2);
      v += __shfl_xor(v, 4);
      if (srcw == 0) rZrow[w * 8 + row8] = 1.0f / v;
    }
    __syncthreads();  // B3
    // --- d: PV with 1/Z folded into V fragments (rZ indexed by k-dim n)
#pragma unroll
    for (int kf = 0; kf < 2; ++kf) {
      if (kf == 1) {
        // overwrite half-tile with nf=2,3 data (same-wave RAW, in-order DS)
#pragma unroll
        for (int nf2 = 0; nf2 < 2; ++nf2)
#pragma unroll
          for (int mf = 0; mf < 4; ++mf)
            if (mf < nmf) {
              uint2 u; u.x = Ppk2[nf2][mf][0]; u.y = Ppk2[nf2][mf][1];
              *(uint2*)(Pw + swzP((uint32_t)((mf * 16 + l15) * 64 + nf2 * 32 + g * 8))) = u;
            }
      }
      f32x4 za = *(const f32x4*)&rZrow[kf * 32 + g * 8];
      f32x4 zb = *(const f32x4*)&rZrow[kf * 32 + g * 8 + 4];
      bf16x8 bV[4];
#pragma unroll
      for (int df = 0; df < 4; ++df) {
        u32x4 vv = *(const u32x4*)(Vtl + it * 8192 +
                                   swz((uint32_t)((df * 16 + l15) * 128 + kf * 64 + g * 16)));
        uint32_t oo[4];
        float2 f0 = unpk_bf16(vv[0]);
        float2 f1 = unpk_bf16(vv[1]);
        float2 f2 = unpk_bf16(vv[2]);
        float2 f3 = unpk_bf16(vv[3]);
        oo[0] = cvt_pk_bf16(f0.x * za[0], f0.y * za[1]);
        oo[1] = cvt_pk_bf16(f1.x * za[2], f1.y * za[3]);
        oo[2] = cvt_pk_bf16(f2.x * zb[0], f2.y * zb[1]);
        oo[3] = cvt_pk_bf16(f3.x * zb[2], f3.y * zb[3]);
        bV[df] = *(bf16x8*)oo;
      }
#pragma unroll
      for (int mf = 0; mf < 4; ++mf)
        if (mf < nmf) {
          bf16x8 aP = *(const bf16x8*)(Pw + swzP((uint32_t)((mf * 16 + l15) * 64 + g * 16)));
#pragma unroll
          for (int df = 0; df < 4; ++df)
            att[mf][df] = __builtin_amdgcn_mfma_f32_16x16x32_bf16(aP, bV[df], att[mf][df], 0, 0, 0);
        }
    }
  }

  // epilogue: bf16 partial att^c at Pp[(c*128+bs)*32768 + m*64 + d]; rows m < 128*(c+1)
  ushort* pb = Pp + ((size_t)c * 128 + bs) * 32768;
#pragma unroll
  for (int mf = 0; mf < 4; ++mf)
    if (mf < nmf) {
#pragma unroll
      for (int df = 0; df < 4; ++df)
#pragma unroll
        for (int r = 0; r < 4; ++r) {
          int m_ = wb + mf * 16 + g * 4 + r;
          pb[(size_t)m_ * 64 + df * 16 + l15] = f2bf(att[mf][df][r]);
        }
    }
}

// ---------------- reduce: out[b,2m',d] = sum over valid chunks, out[b,odd,d] = 0 ----------------
__global__ void reduce_kernel(const ushort* __restrict__ Pp, float* __restrict__ out) {
  // XCD swizzle: blocks for segment bs land on XCD bs%8 (same L2 as attn partial writes)
  const int bid = blockIdx.x;
  const int xcd = bid & 7, idx = bid >> 3;
  const int bs = (idx & 15) * 8 + xcd;
  const int inner = idx >> 4;
  int jj = bs * 4096 + inner * 256 + threadIdx.x;
  int d8 = jj & 7, m = (jj >> 3) & 511;
  const size_t ji = ((size_t)bs * 512 + m) * 64 + d8 * 8;
  float f[8];
#pragma unroll
  for (int e = 0; e < 8; ++e) f[e] = 0.f;
  for (int cc = m >> 7; cc < 4; ++cc) {  // chunk cc covers m < 128*(cc+1)
    uint4 v = *(const uint4*)(Pp + (size_t)cc * 4194304 + ji);
    uint32_t dw[4] = {v.x, v.y, v.z, v.w};
#pragma unroll
    for (int t = 0; t < 4; ++t) {
      f[t * 2] += __uint_as_float(dw[t] << 16);
      f[t * 2 + 1] += __uint_as_float(dw[t] & 0xffff0000u);
    }
  }
  int b = bs >> 4, s = bs & 15;
  size_t t0 = 2 * ((size_t)s * 512 + m);
  float* ob = out + (size_t)b * 1048576 + t0 * 64 + d8 * 8;
  *(float4*)(ob) = (float4){f[0], f[1], f[2], f[3]};
  *(float4*)(ob + 4) = (float4){f[4], f[5], f[6], f[7]};
  *(float4*)(ob + 64) = (float4){0.f, 0.f, 0.f, 0.f};
  *(float4*)(ob + 68) = (float4){0.f, 0.f, 0.f, 0.f};
}

extern "C" void kernel_launch(void* const* d_in, const int* in_sizes, int n_in,
                              void* d_out, int out_size, void* d_ws, size_t ws_size,
                              hipStream_t stream) {
  const float* x  = (const float*)d_in[0];
  const float* Wk = (const float*)d_in[1];
  const float* Wq = (const float*)d_in[2];
  const float* Wv = (const float*)d_in[3];
  const float* PE = (const float*)d_in[4];
  float* out = (float*)d_out;
  char* ws = (char*)d_ws;

  ushort* Qw   = (ushort*)(ws);              // 8 MB
  ushort* Kw   = (ushort*)(ws + 8388608);    // 8 MB
  ushort* Vw   = (ushort*)(ws + 16777216);   // 8 MB
  ushort* Wp   = (ushort*)(ws + 25165824);   // 192 KB
  float*  PEdT = (float*)(ws + 25362432);    // 1 MB
  ushort* Pp   = (ushort*)(ws + 33554432);   // 32 MB partials (4 chunks)

  pack_kernel<<<dim3(1408), dim3(256), 0, stream>>>(Wk, Wq, Wv, PE, Wp, PEdT);
  proj_kernel<<<dim3(512), dim3(512), 0, stream>>>(x, Wp, Qw, Kw, Vw);
  attn_kernel<<<dim3(512), dim3(512), 0, stream>>>(Qw, Kw, Vw, PEdT, Pp);
  reduce_kernel<<<dim3(2048), dim3(256), 0, stream>>>(Pp, out);
}